// Round 2
// 64.866 us; speedup vs baseline: 1.0193x; 1.0193x over previous
//
#include <hip/hip_runtime.h>

// Problem constants (from reference): V=16, T=2048, D=1, K=16
#define NV 16
#define NT 2048
#define NK 16
#define BLK 128                               // threads per block
#define BPV ((NT - NK + BLK - 1) / BLK)       // 16 blocks per video
#define WIN (BLK + NK + 1)                    // 145-float staging window

// One thread per output row i in [K, T). t is sorted along T and D==1, so
// score -(t_i - t_j)^2 is nondecreasing in j for j < i: top-k = last-k window.
// The ONLY way the answer differs from [i-1, i-2, ..., i-16] is bit-equal
// timestamp ties (stable top_k reorders tie-groups to ascending index and
// truncates the boundary group to its lowest indices). Ties are rare: detect
// them with 16 adjacent-pair compares over ts[i-17..i-1]; fast path writes the
// window directly, slow path does the tie-group walk (direct global writes —
// no runtime-indexed local array, so no scratch allocation).
__global__ __launch_bounds__(BLK) void topk_rows_kernel(
    const float* __restrict__ t,      // (V, T, 1) float32, sorted along T
    const int* __restrict__ mask,     // (V, T, 1) bool->int32 prefix mask
    int* __restrict__ out)            // (V, T-K, K) int32
{
    __shared__ float ts[WIN];

    const int v = blockIdx.x / BPV;
    const int b = blockIdx.x % BPV;
    const int base = NK + b * BLK;            // first output row of this block
    const int wstart = base - NK - 1;         // lowest t-index needed (>= -1)

    // Stage the 145-float window this block needs. g == -1 only for b == 0;
    // sentinel -1.0f can never equal a timestamp (timestamps are >= 0).
    for (int j = (int)threadIdx.x; j < WIN; j += BLK) {
        const int g = wstart + j;
        ts[j] = (g >= 0) ? t[v * NT + g] : -1.0f;
    }
    __syncthreads();

    const int i = base + (int)threadIdx.x;
    if (i >= NT) return;

    int* orow = out + ((size_t)v * (NT - NK) + (i - NK)) * NK;

    // valid iff i < seq_len[v] iff mask[v][i] nonzero (mask is a prefix mask)
    if (mask[v * NT + i] == 0) {
        const int4 z = make_int4(0, 0, 0, 0);
        int4* o4 = (int4*)orow;
        o4[0] = z; o4[1] = z; o4[2] = z; o4[3] = z;
        return;
    }

    // Tie detection over ts[i-17 .. i-1]: 17 independent LDS reads (stride-1
    // across lanes -> 2-way bank aliasing, free), 16 compares.
    const int li = NK + 1 + (int)threadIdx.x;  // position of row i in ts[]
    bool tie = false;
    float prev = ts[li - NK - 1];
    #pragma unroll
    for (int s = NK; s >= 1; --s) {
        const float cur = ts[li - s];
        tie |= (cur == prev);
        prev = cur;
    }

    if (!tie) {
        // No ties in or adjacent to the window: answer is i-1 .. i-16.
        int4* o4 = (int4*)orow;
        o4[0] = make_int4(i - 1,  i - 2,  i - 3,  i - 4);
        o4[1] = make_int4(i - 5,  i - 6,  i - 7,  i - 8);
        o4[2] = make_int4(i - 9,  i - 10, i - 11, i - 12);
        o4[3] = make_int4(i - 13, i - 14, i - 15, i - 16);
        return;
    }

    // Slow path (rare): walk backward over runs of equal timestamps. Runs may
    // extend beyond the staged window, so read global directly (t is 128 KB
    // total -> L1/L2 resident). Each run is one tie-group: emit ascending
    // indices within the group; truncate the final group to its lowest
    // indices (stable top_k semantics). Writes go straight to orow.
    const float* tv = t + v * NT;
    int slot = 0;
    int j = i - 1;
    while (slot < NK && j >= 0) {
        const float val = tv[j];
        int p = j;
        while (p > 0 && tv[p - 1] == val) --p;
        const int run = j - p + 1;
        const int take = (run < NK - slot) ? run : (NK - slot);
        for (int r = 0; r < take; ++r) orow[slot + r] = p + r;
        slot += take;
        j = p - 1;
    }
    for (; slot < NK; ++slot) orow[slot] = 0;
}

extern "C" void kernel_launch(void* const* d_in, const int* in_sizes, int n_in,
                              void* d_out, int out_size, void* d_ws, size_t ws_size,
                              hipStream_t stream) {
    const float* t    = (const float*)d_in[0];   // (V,T,1) float32
    const int*   mask = (const int*)d_in[1];     // (V,T,1) bool (int32 on device)
    // d_in[2] is k == 16, compile-time constant here.
    int* out = (int*)d_out;                      // (V, T-K, K) int32

    topk_rows_kernel<<<dim3(NV * BPV), dim3(BLK), 0, stream>>>(t, mask, out);
}